// Round 5
// baseline (125.567 us; speedup 1.0000x reference)
//
#include <hip/hip_runtime.h>
#include <math.h>

// Problem shape (fixed by setup_inputs)
constexpr int B = 16, H = 384, W = 1280;
constexpr int HW = H * W;
constexpr int NPIX = B * HW;             // 7,864,320
constexpr int HW4 = HW / 4;              // 122,880 float4 granules per batch image
constexpr int W4 = W / 4;                // 320
constexpr int NBLOCKS = 2048;
constexpr int NTHREADS = 256;
constexpr int NXCD = 8;
constexpr int BLK_PER_XCD = NBLOCKS / NXCD;            // 256
constexpr int THR_PER_XCD = BLK_PER_XCD * NTHREADS;    // 65536 (multiple of 256)
constexpr int NTASK = 2 * HW4;                          // 245,760 tasks per XCD
constexpr float EPSV = 1e-8f;

// ws float layout: [0,384) per-batch params (24 floats each); [384,384+NBLOCKS) block partials
constexpr int PARAMS_FLOATS = B * 24;

__device__ inline void aa_to_R(float x, float y, float z, float R[9]) {
    float t2 = x * x + y * y + z * z;
    float th = sqrtf(t2 + 1e-12f);
    float A = sinf(th) / th;
    float Bc = (1.0f - cosf(th)) / (t2 + 1e-12f);
    R[0] = 1.0f + Bc * (-(y * y + z * z));
    R[1] = A * (-z) + Bc * (x * y);
    R[2] = A * ( y) + Bc * (x * z);
    R[3] = A * ( z) + Bc * (x * y);
    R[4] = 1.0f + Bc * (-(x * x + z * z));
    R[5] = A * (-x) + Bc * (y * z);
    R[6] = A * (-y) + Bc * (x * z);
    R[7] = A * ( x) + Bc * (y * z);
    R[8] = 1.0f + Bc * (-(x * x + y * y));
}

__device__ inline void mat3_mul(const float* A, const float* Bm, float* C) {
#pragma unroll
    for (int i = 0; i < 3; i++)
#pragma unroll
        for (int j = 0; j < 3; j++)
            C[i * 3 + j] = A[i * 3 + 0] * Bm[0 * 3 + j]
                         + A[i * 3 + 1] * Bm[1 * 3 + j]
                         + A[i * 3 + 2] * Bm[2 * 3 + j];
}

__device__ inline void compute_dir(const float Ra[9], const float Rb[9],
                                   const float ta[3], const float tb[3],
                                   const float K[9], const float Ki[9],
                                   float* out) {
    float Rrel[9];
#pragma unroll
    for (int i = 0; i < 3; i++)
#pragma unroll
        for (int j = 0; j < 3; j++)
            Rrel[i * 3 + j] = Ra[0 * 3 + i] * Rb[0 * 3 + j]
                            + Ra[1 * 3 + i] * Rb[1 * 3 + j]
                            + Ra[2 * 3 + i] * Rb[2 * 3 + j];
    float dt[3] = { tb[0] - ta[0], tb[1] - ta[1], tb[2] - ta[2] };
    float trel[3];
#pragma unroll
    for (int i = 0; i < 3; i++)
        trel[i] = Ra[0 * 3 + i] * dt[0] + Ra[1 * 3 + i] * dt[1] + Ra[2 * 3 + i] * dt[2];
    float tmp[9], M[9];
    mat3_mul(Rrel, Ki, tmp);
    mat3_mul(K, tmp, M);
#pragma unroll
    for (int i = 0; i < 9; i++) out[i] = M[i];
#pragma unroll
    for (int i = 0; i < 3; i++)
        out[9 + i] = K[i * 3 + 0] * trel[0] + K[i * 3 + 1] * trel[1] + K[i * 3 + 2] * trel[2];
}

__global__ void grl_setup_kernel(const float* __restrict__ cpos, const float* __restrict__ npos,
                                 const float* __restrict__ cang, const float* __restrict__ nang,
                                 const float* __restrict__ Kmat, float* __restrict__ ws) {
    int b = threadIdx.x;
    if (b >= B) return;
    float Rc[9], Rn[9];
    aa_to_R(cang[3 * b + 0], cang[3 * b + 1], cang[3 * b + 2], Rc);
    aa_to_R(nang[3 * b + 0], nang[3 * b + 1], nang[3 * b + 2], Rn);
    float tc[3] = { cpos[3 * b + 0], cpos[3 * b + 1], cpos[3 * b + 2] };
    float tn[3] = { npos[3 * b + 0], npos[3 * b + 1], npos[3 * b + 2] };
    float K[9];
#pragma unroll
    for (int i = 0; i < 9; i++) K[i] = Kmat[i];
    float det = K[0] * (K[4] * K[8] - K[5] * K[7])
              - K[1] * (K[3] * K[8] - K[5] * K[6])
              + K[2] * (K[3] * K[7] - K[4] * K[6]);
    float id = 1.0f / det;
    float Ki[9] = {
        (K[4] * K[8] - K[5] * K[7]) * id, (K[2] * K[7] - K[1] * K[8]) * id, (K[1] * K[5] - K[2] * K[4]) * id,
        (K[5] * K[6] - K[3] * K[8]) * id, (K[0] * K[8] - K[2] * K[6]) * id, (K[2] * K[3] - K[0] * K[5]) * id,
        (K[3] * K[7] - K[4] * K[6]) * id, (K[1] * K[6] - K[0] * K[7]) * id, (K[0] * K[4] - K[1] * K[3]) * id };
    float* out = ws + b * 24;
    compute_dir(Rc, Rn, tc, tn, K, Ki, out);        // dir0: T_n2c
    compute_dir(Rn, Rc, tn, tc, K, Ki, out + 12);   // dir1: T_c2n
}

// 8-byte pair load at 4B alignment (legal lowering chosen by compiler).
__device__ inline float2 load2u(const float* __restrict__ p) {
    float2 v;
    __builtin_memcpy(&v, p, sizeof(float2));
    return v;
}

// Pipeline stage: 16 in-flight pair loads + folded bilinear coefficients.
// g = p0.x*c00 + p0.y*c01 + p1.x*c10 + p1.y*c11  (selects folded into c's)
struct Stage {
    float2 p0[8], p1[8];              // [dir*4+k], rows y0/y1
    float  c00[8], c01[8], c10[8], c11[8];
    float  dst[8];
};

__device__ inline void issue_stage(int t, int xcd,
                                   const float* __restrict__ cur,
                                   const float* __restrict__ nxt,
                                   const float* __restrict__ ws, Stage& S) {
    int bl  = (t >= HW4) ? 1 : 0;      // wave-uniform (strides multiple of 256)
    int idx = t - bl * HW4;
    int b   = xcd * 2 + bl;
    const float* __restrict__ prm = ws + b * 24;
    const float* __restrict__ img0 = cur + b * HW;   // dir0 samples cur
    const float* __restrict__ img1 = nxt + b * HW;   // dir1 samples nxt
    int h  = idx / W4;
    int w4 = idx - h * W4;
    int p  = idx * 4;
    const float4 c4 = *(const float4*)(img0 + p);
    const float4 n4 = *(const float4*)(img1 + p);
    float fh = (float)h;
    float dstv[2][4] = { { n4.x, n4.y, n4.z, n4.w },
                         { c4.x, c4.y, c4.z, c4.w } };
#pragma unroll
    for (int dir = 0; dir < 2; dir++) {
        const float* __restrict__ img = dir ? img1 : img0;
        float M0 = prm[dir * 12 + 0], M1 = prm[dir * 12 + 1], M2 = prm[dir * 12 + 2];
        float M3 = prm[dir * 12 + 3], M4 = prm[dir * 12 + 4], M5 = prm[dir * 12 + 5];
        float M6 = prm[dir * 12 + 6], M7 = prm[dir * 12 + 7], M8 = prm[dir * 12 + 8];
        float k0 = prm[dir * 12 + 9], k1 = prm[dir * 12 + 10], k2 = prm[dir * 12 + 11];
        float rx = M1 * fh + M2;
        float ry = M4 * fh + M5;
        float rz = M7 * fh + M8;
#pragma unroll
        for (int k = 0; k < 4; k++) {
            int i = dir * 4 + k;
            float fw = (float)(w4 * 4 + k);
            float d  = dstv[dir][k];
            float px = d * (M0 * fw + rx) + k0;
            float py = d * (M3 * fw + ry) + k1;
            float pz = d * (M6 * fw + rz) + k2;
            float scale = (fabsf(pz) > EPSV) ? (1.0f / pz) : 1.0f;
            float ix = px * scale, iy = py * scale;
            float x0f = floorf(ix), y0f = floorf(iy);
            float wx1 = ix - x0f, wy1 = iy - y0f;
            float wx0 = 1.0f - wx1, wy0 = 1.0f - wy1;
            bool vx0 = (x0f >= 0.0f)        & (x0f <= (float)(W - 1));
            bool vx1 = (x0f + 1.0f >= 0.0f) & (x0f + 1.0f <= (float)(W - 1));
            bool vy0 = (y0f >= 0.0f)        & (y0f <= (float)(H - 1));
            bool vy1 = (y0f + 1.0f >= 0.0f) & (y0f + 1.0f <= (float)(H - 1));
            float mxl = vx0 ? wx0 : 0.0f;
            float mxr = vx1 ? wx1 : 0.0f;
            float myt = vy0 ? wy0 : 0.0f;
            float myb = vy1 ? wy1 : 0.0f;
            int xi0 = (int)fminf(fmaxf(x0f,        0.0f), (float)(W - 1));
            int xi1 = (int)fminf(fmaxf(x0f + 1.0f, 0.0f), (float)(W - 1));
            int yi0 = (int)fminf(fmaxf(y0f,        0.0f), (float)(H - 1));
            int yi1 = (int)fminf(fmaxf(y0f + 1.0f, 0.0f), (float)(H - 1));
            int xp  = min(xi0, W - 2);
            int sL = xi0 - xp, sR = xi1 - xp;     // 0/1 selects within pair
            float ax = (sL ? 0.0f : mxl) + (sR ? 0.0f : mxr);   // weight on p.x
            float bx = (sL ? mxl : 0.0f) + (sR ? mxr : 0.0f);   // weight on p.y
            S.c00[i] = ax * myt;
            S.c01[i] = bx * myt;
            S.c10[i] = ax * myb;
            S.c11[i] = bx * myb;
            S.dst[i] = d;
            S.p0[i] = load2u(img + yi0 * W + xp);
            S.p1[i] = load2u(img + yi1 * W + xp);
        }
    }
}

__device__ inline float consume_stage(const Stage& S) {
    float s = 0.0f;
#pragma unroll
    for (int i = 0; i < 8; i++) {
        float g = S.p0[i].x * S.c00[i] + S.p0[i].y * S.c01[i]
                + S.p1[i].x * S.c10[i] + S.p1[i].y * S.c11[i];
        s += fabsf(g - S.dst[i]);
    }
    return s;
}

// R1: batch<->XCD pinning (3.9 MB/batch fits one XCD's 4 MiB L2).
// R4: clustered pair-loads (+sched_barrier).
// R5: fully-unrolled 2-deep software pipeline over <=4 flattened (batch,granule)
//     tasks per thread -> ~36 VMEM ops in flight per wave at every wait point.
__global__ __launch_bounds__(NTHREADS, 2) void grl_warp_loss_kernel(
        const float* __restrict__ cur, const float* __restrict__ nxt,
        const float* __restrict__ ws, float* __restrict__ partials) {
    int bid = blockIdx.x;
    int xcd = bid & (NXCD - 1);
    int j   = bid >> 3;
    int tid0 = j * NTHREADS + (int)threadIdx.x;   // 0..65535
    float sum = 0.0f;

    Stage A, Bs;
    // tasks t0..t2 always valid (tid0 + 2*65536 <= 196607 < 245760)
    issue_stage(tid0,                 xcd, cur, nxt, ws, A);
    issue_stage(tid0 + THR_PER_XCD,   xcd, cur, nxt, ws, Bs);
    __builtin_amdgcn_sched_barrier(0);
    sum += consume_stage(A);
    issue_stage(tid0 + 2 * THR_PER_XCD, xcd, cur, nxt, ws, A);
    __builtin_amdgcn_sched_barrier(0);
    sum += consume_stage(Bs);
    int t3 = tid0 + 3 * THR_PER_XCD;
    if (t3 < NTASK) {
        issue_stage(t3, xcd, cur, nxt, ws, Bs);
        __builtin_amdgcn_sched_barrier(0);
        sum += consume_stage(A);
        sum += consume_stage(Bs);
    } else {
        sum += consume_stage(A);
    }

#pragma unroll
    for (int off2 = 32; off2 > 0; off2 >>= 1) sum += __shfl_down(sum, off2, 64);
    __shared__ float smem[NTHREADS / 64];
    int lane = threadIdx.x & 63, wid = threadIdx.x >> 6;
    if (lane == 0) smem[wid] = sum;
    __syncthreads();
    if (threadIdx.x == 0) {
        float t = 0.0f;
#pragma unroll
        for (int i = 0; i < NTHREADS / 64; i++) t += smem[i];
        partials[blockIdx.x] = t;
    }
}

__global__ __launch_bounds__(256) void grl_finalize_kernel(const float* __restrict__ partials,
                                                           float* __restrict__ out) {
    float sum = 0.0f;
    for (int i = threadIdx.x; i < NBLOCKS; i += 256) sum += partials[i];
#pragma unroll
    for (int off = 32; off > 0; off >>= 1) sum += __shfl_down(sum, off, 64);
    __shared__ float smem[4];
    int lane = threadIdx.x & 63, wid = threadIdx.x >> 6;
    if (lane == 0) smem[wid] = sum;
    __syncthreads();
    if (threadIdx.x == 0) {
        float t = smem[0] + smem[1] + smem[2] + smem[3];
        out[0] = t * (0.1f / (2.0f * (float)NPIX));
    }
}

extern "C" void kernel_launch(void* const* d_in, const int* in_sizes, int n_in,
                              void* d_out, int out_size, void* d_ws, size_t ws_size,
                              hipStream_t stream) {
    const float* cur  = (const float*)d_in[0];
    const float* nxt  = (const float*)d_in[1];
    const float* cpos = (const float*)d_in[2];
    const float* npos = (const float*)d_in[3];
    const float* cang = (const float*)d_in[4];
    const float* nang = (const float*)d_in[5];
    const float* Kmat = (const float*)d_in[6];
    float* ws = (float*)d_ws;
    float* partials = ws + PARAMS_FLOATS;

    grl_setup_kernel<<<1, 64, 0, stream>>>(cpos, npos, cang, nang, Kmat, ws);
    grl_warp_loss_kernel<<<NBLOCKS, NTHREADS, 0, stream>>>(cur, nxt, ws, partials);
    grl_finalize_kernel<<<1, 256, 0, stream>>>(partials, (float*)d_out);
}